// Round 7
// baseline (155.126 us; speedup 1.0000x reference)
//
#include <hip/hip_runtime.h>

#define H 65536
#define CIN 64
#define COUT 128
#define NK 27
#define KTOT (NK*CIN)   // 1728
#define NBLK 64         // points per block; 4 waves, each 32o x 64n

typedef unsigned short u16;
typedef unsigned int   u32;
typedef __attribute__((ext_vector_type(8))) short short8;   // 8 bf16 (MFMA frag)
typedef __attribute__((ext_vector_type(4))) float f32x4;    // MFMA acc
typedef __attribute__((ext_vector_type(4))) unsigned int u32x4;

__device__ __forceinline__ u16 f2bf(float f) {
    u32 u = __float_as_uint(f);
    u = (u + 0x7FFFu + ((u >> 16) & 1u)) >> 16;   // RNE
    return (u16)u;
}

// ---------------------------------------------------------------------------
// Kernel 1a: x (64 x 65536 f32, c-major) -> x_t (65536 x 64 bf16, point-major)
__global__ __launch_bounds__(256) void transpose_x(const float* __restrict__ x,
                                                   u16* __restrict__ xt) {
    const int h = blockIdx.x * 256 + threadIdx.x;
    u32 pk[32];
#pragma unroll
    for (int cp = 0; cp < 32; ++cp) {
        float f0 = x[(2 * cp)     * H + h];
        float f1 = x[(2 * cp + 1) * H + h];
        pk[cp] = (u32)f2bf(f0) | ((u32)f2bf(f1) << 16);
    }
    u32x4* dst = (u32x4*)(xt + (size_t)h * CIN);
#pragma unroll
    for (int i = 0; i < 8; ++i)
        dst[i] = *(u32x4*)&pk[i * 4];
}

// ---------------------------------------------------------------------------
// Kernel 1b: w (128 x 64 x 27 f32) -> wb[o][k*64+c] bf16 (R1 layout).
// Also zeroes BN sums.
__global__ __launch_bounds__(256) void conv_w(const float* __restrict__ w,
                                              u16* __restrict__ wb,
                                              float* __restrict__ sums) {
    const int tid = blockIdx.x * 256 + threadIdx.x;
    if (blockIdx.x == 0) sums[threadIdx.x] = 0.f;   // sum[128], sumsq[128]
    if (tid < COUT * KTOT) {
        const int o = tid / KTOT;
        const int rem = tid - o * KTOT;
        const int k = rem >> 6;
        const int c = rem & 63;
        wb[tid] = f2bf(w[o * KTOT + c * NK + k]);
    }
}

// ---------------------------------------------------------------------------
// Kernel 2: R1's structure with ONE change: queue-order-correct 3-deep gather.
// Per body k: barrier; WRITEB g(k+1) [issued k-2, vmcnt(6), ~2 bodies cover];
// A_LOAD(k+1); GATHER(k+3); barrier; MFMA(k) [waits A(k) at vmcnt(8) --
// g(k+2), g(k+3) are NEWER in queue so they stay in flight].
__global__ __launch_bounds__(256, 4) void conv_mfma(const u16* __restrict__ xt,
                                                    const u16* __restrict__ wb,
                                                    const int* __restrict__ neigh,
                                                    float* __restrict__ out,
                                                    float* __restrict__ sums) {
    __shared__ __align__(16) u16 sB[2][NBLK * CIN];  // 2 x 8 KB, XOR-swizzled
    __shared__ int sIdx[NBLK * NK];                  // 6912 B

    const int tid  = threadIdx.x;
    const int lane = tid & 63;
    const int w    = tid >> 6;        // wave 0..3 -> o-range w*32..+31
    const int n0   = blockIdx.x * NBLK;

    for (int i = tid; i < NBLK * NK; i += 256)
        sIdx[i] = neigh[n0 * NK + i];
    __syncthreads();

    const int r16 = lane & 15;
    const int q   = lane >> 4;        // 0..3
    const int kc  = q * 8;
    const int pl  = lane >> 3;        // 0..7 row-within-8
    const int cl  = lane & 7;         // 16B chunk within 128B row

    f32x4 acc[2][4] = {};             // [o-frag][n-frag]

    u32x4 rgA[2], rgB[2];             // 2 sets carry a 3-deep pipeline
    short8 afA[2][2], afB[2][2];      // A double buffer [f][hh]

#define GATHER(K, RG)                                                        \
    { _Pragma("unroll") for (int it = 0; it < 2; ++it) {                     \
        const int p_ = w * 16 + it * 8 + pl;                                 \
        const int row_ = sIdx[p_ * NK + (K)];                                \
        RG[it] = *(const u32x4*)(xt + (size_t)(u32)row_ * 64 + cl * 8); } }
#define WRITEB(RG, BUF)                                                      \
    { _Pragma("unroll") for (int it = 0; it < 2; ++it) {                     \
        const int p_ = w * 16 + it * 8 + pl;                                 \
        *(u32x4*)((BUF) + p_ * 64 + ((cl ^ pl) * 8)) = RG[it]; } }
#define A_LOAD(K, AF)                                                        \
    { _Pragma("unroll") for (int hh = 0; hh < 2; ++hh)                       \
      _Pragma("unroll") for (int f = 0; f < 2; ++f) {                        \
        const int o_ = w * 32 + f * 16 + r16;                                \
        AF[f][hh] = *(const short8*)(wb + (size_t)o_ * KTOT +                \
                                     (K) * CIN + hh * 32 + kc); } }
#define MFMA_STEP(K, AF)                                                     \
    { _Pragma("unroll") for (int hh = 0; hh < 2; ++hh) {                     \
        short8 bfr[4];                                                       \
        _Pragma("unroll") for (int nf = 0; nf < 4; ++nf) {                   \
            const int p_ = nf * 16 + r16;                                    \
            const int sl_ = (hh * 4 + q) ^ (p_ & 7);                         \
            bfr[nf] = *(const short8*)(&sB[(K) & 1][p_ * 64 + sl_ * 8]);     \
        }                                                                    \
        _Pragma("unroll") for (int f = 0; f < 2; ++f)                        \
        _Pragma("unroll") for (int nf = 0; nf < 4; ++nf)                     \
            acc[f][nf] = __builtin_amdgcn_mfma_f32_16x16x32_bf16(            \
                AF[f][hh], bfr[nf], acc[f][nf], 0, 0, 0);                    \
    } }

// BODY(K): WSET = reg set holding g(K+1) (reused for g(K+3));
//          ANEXT = A buffer for K+1; ACUR = A buffer for K.
#define BODY(K, WSET, ANEXT, ACUR)                                           \
    {                                                                        \
        __syncthreads();                                                     \
        if ((K) + 1 < NK) WRITEB(WSET, &sB[((K) + 1) & 1][0])                \
        if ((K) + 1 < NK) A_LOAD((K) + 1, ANEXT)                             \
        if ((K) + 3 < NK) GATHER((K) + 3, WSET)                              \
        __syncthreads();                                                     \
        MFMA_STEP(K, ACUR)                                                   \
    }

    // prologue: buf0 staged; g(1)->rgB, g(2)->rgA in flight; A(0) loaded
    GATHER(0, rgA)
    WRITEB(rgA, &sB[0][0])
    A_LOAD(0, afA)
    GATHER(1, rgB)
    GATHER(2, rgA)

    for (int k = 0; k < NK - 1; k += 2) {   // k = 0,2,...,24
        BODY(k,     rgB, afB, afA)
        BODY(k + 1, rgA, afA, afB)
    }
    BODY(26, rgB, afB, afA)                  // guards disable WR/A/G

#undef GATHER
#undef WRITEB
#undef A_LOAD
#undef MFMA_STEP
#undef BODY

    // epilogue: C/D layout: col(n) = lane&15, row(o) = q*4 + r
#pragma unroll
    for (int f = 0; f < 2; ++f)
#pragma unroll
        for (int nf = 0; nf < 4; ++nf)
#pragma unroll
            for (int r = 0; r < 4; ++r) {
                const int o = w * 32 + f * 16 + q * 4 + r;
                const int n = n0 + nf * 16 + r16;
                out[(size_t)o * H + n] = acc[f][nf][r];
            }

    // fused BN partial sums: reduce this wave's 64 n per o, one atomic per o
#pragma unroll
    for (int f = 0; f < 2; ++f)
#pragma unroll
        for (int r = 0; r < 4; ++r) {
            float sv = acc[f][0][r] + acc[f][1][r] + acc[f][2][r] + acc[f][3][r];
            float sq = acc[f][0][r] * acc[f][0][r] + acc[f][1][r] * acc[f][1][r]
                     + acc[f][2][r] * acc[f][2][r] + acc[f][3][r] * acc[f][3][r];
#pragma unroll
            for (int m = 1; m < 16; m <<= 1) {
                sv += __shfl_xor(sv, m, 64);
                sq += __shfl_xor(sq, m, 64);
            }
            if (r16 == 0) {
                const int o = w * 32 + f * 16 + q * 4 + r;
                atomicAdd(&sums[o], sv);
                atomicAdd(&sums[COUT + o], sq);
            }
        }
}

// ---------------------------------------------------------------------------
// Kernel 3: BN + ReLU with inline stats (sums accumulated by conv), float4.
__global__ __launch_bounds__(256) void bn_relu(float* __restrict__ out,
                                               const float* __restrict__ sums,
                                               const float* __restrict__ gamma,
                                               const float* __restrict__ beta) {
    const int idx = blockIdx.x * 256 + threadIdx.x;  // float4 index
    const int o = idx >> 14;                          // 16384 float4 per channel
    const float mean = sums[o] * (1.f / (float)H);
    const float var  = sums[COUT + o] * (1.f / (float)H) - mean * mean;
    const float a = gamma[o] * rsqrtf(var + 1e-5f);
    const float b = beta[o] - mean * a;
    float4* p = (float4*)out;
    float4 v = p[idx];
    v.x = fmaxf(fmaf(v.x, a, b), 0.f);
    v.y = fmaxf(fmaf(v.y, a, b), 0.f);
    v.z = fmaxf(fmaf(v.z, a, b), 0.f);
    v.w = fmaxf(fmaf(v.w, a, b), 0.f);
    p[idx] = v;
}

// ---------------------------------------------------------------------------
extern "C" void kernel_launch(void* const* d_in, const int* in_sizes, int n_in,
                              void* d_out, int out_size, void* d_ws, size_t ws_size,
                              hipStream_t stream) {
    const float* x     = (const float*)d_in[0];  // (1,64,65536,1)
    const int*   neigh = (const int*)d_in[1];    // (65536,27)
    const float* w     = (const float*)d_in[2];  // (128,64,27)
    const float* gamma = (const float*)d_in[3];
    const float* beta  = (const float*)d_in[4];
    float* out = (float*)d_out;                  // (1,128,65536,1)

    char* ws = (char*)d_ws;
    u16* xt  = (u16*)ws;                              // 8388608 B
    u16* wb  = (u16*)(ws + 8388608);                  // 442368 B
    float* sums = (float*)(ws + 8388608 + 442368);    // 256 floats

    transpose_x<<<H / 256, 256, 0, stream>>>(x, xt);
    conv_w<<<(COUT * KTOT + 255) / 256, 256, 0, stream>>>(w, wb, sums);
    conv_mfma<<<H / NBLK, 256, 0, stream>>>(xt, wb, neigh, out, sums);
    bn_relu<<<(COUT * H / 4) / 256, 256, 0, stream>>>(out, sums, gamma, beta);
}

// Round 8
// 91.025 us; speedup vs baseline: 1.7042x; 1.7042x over previous
//
#include <hip/hip_runtime.h>

#define H 65536
#define CIN 64
#define COUT 128
#define NK 27
#define KTOT (NK*CIN)   // 1728
#define NBLK 64         // points per block; 4 waves, each 32o x 64n
#define NBLOCKS (H/NBLK) // 1024

typedef unsigned short u16;
typedef unsigned int   u32;
typedef __attribute__((ext_vector_type(8))) short short8;   // 8 bf16 (MFMA frag)
typedef __attribute__((ext_vector_type(4))) float f32x4;    // MFMA acc
typedef __attribute__((ext_vector_type(4))) unsigned int u32x4;

__device__ __forceinline__ u16 f2bf(float f) {
    u32 u = __float_as_uint(f);
    u = (u + 0x7FFFu + ((u >> 16) & 1u)) >> 16;   // RNE
    return (u16)u;
}

// ---------------------------------------------------------------------------
// Kernel 1a: x (64 x 65536 f32, c-major) -> x_t (65536 x 64 bf16, point-major)
__global__ __launch_bounds__(256) void transpose_x(const float* __restrict__ x,
                                                   u16* __restrict__ xt) {
    const int h = blockIdx.x * 256 + threadIdx.x;
    u32 pk[32];
#pragma unroll
    for (int cp = 0; cp < 32; ++cp) {
        float f0 = x[(2 * cp)     * H + h];
        float f1 = x[(2 * cp + 1) * H + h];
        pk[cp] = (u32)f2bf(f0) | ((u32)f2bf(f1) << 16);
    }
    u32x4* dst = (u32x4*)(xt + (size_t)h * CIN);
#pragma unroll
    for (int i = 0; i < 8; ++i)
        dst[i] = *(u32x4*)&pk[i * 4];
}

// ---------------------------------------------------------------------------
// Kernel 1b: w (128 x 64 x 27 f32) -> wb[o][k*64+c] bf16. Also zeroes BN sums.
__global__ __launch_bounds__(256) void conv_w(const float* __restrict__ w,
                                              u16* __restrict__ wb,
                                              float* __restrict__ sums) {
    const int tid = blockIdx.x * 256 + threadIdx.x;
    if (blockIdx.x == 0) sums[threadIdx.x] = 0.f;   // sum[128], sumsq[128]
    if (tid < COUT * KTOT) {
        const int o = tid / KTOT;
        const int rem = tid - o * KTOT;
        const int k = rem >> 6;
        const int c = rem & 63;
        wb[tid] = f2bf(w[o * KTOT + c * NK + k]);
    }
}

// ---------------------------------------------------------------------------
// Kernel 2: R7's 3-deep queue-order-correct pipeline; epilogue writes per-block
// BN partials to global scratch (coalesced, ZERO atomics — R2-R7's 262K
// same-line atomics were a ~70us serialization floor).
__global__ __launch_bounds__(256, 4) void conv_mfma(const u16* __restrict__ xt,
                                                    const u16* __restrict__ wb,
                                                    const int* __restrict__ neigh,
                                                    float* __restrict__ out,
                                                    float* __restrict__ part) {
    __shared__ __align__(16) u16 sB[2][NBLK * CIN];  // 2 x 8 KB, XOR-swizzled
    __shared__ int sIdx[NBLK * NK];                  // 6912 B (reused as f32[256])

    const int tid  = threadIdx.x;
    const int lane = tid & 63;
    const int w    = tid >> 6;        // wave 0..3 -> o-range w*32..+31
    const int n0   = blockIdx.x * NBLK;

    for (int i = tid; i < NBLK * NK; i += 256)
        sIdx[i] = neigh[n0 * NK + i];
    __syncthreads();

    const int r16 = lane & 15;
    const int q   = lane >> 4;        // 0..3
    const int kc  = q * 8;
    const int pl  = lane >> 3;        // 0..7 row-within-8
    const int cl  = lane & 7;         // 16B chunk within 128B row

    f32x4 acc[2][4] = {};             // [o-frag][n-frag]

    u32x4 rgA[2], rgB[2];             // 2 sets carry a 3-deep pipeline
    short8 afA[2][2], afB[2][2];      // A double buffer [f][hh]

#define GATHER(K, RG)                                                        \
    { _Pragma("unroll") for (int it = 0; it < 2; ++it) {                     \
        const int p_ = w * 16 + it * 8 + pl;                                 \
        const int row_ = sIdx[p_ * NK + (K)];                                \
        RG[it] = *(const u32x4*)(xt + (size_t)(u32)row_ * 64 + cl * 8); } }
#define WRITEB(RG, BUF)                                                      \
    { _Pragma("unroll") for (int it = 0; it < 2; ++it) {                     \
        const int p_ = w * 16 + it * 8 + pl;                                 \
        *(u32x4*)((BUF) + p_ * 64 + ((cl ^ pl) * 8)) = RG[it]; } }
#define A_LOAD(K, AF)                                                        \
    { _Pragma("unroll") for (int hh = 0; hh < 2; ++hh)                       \
      _Pragma("unroll") for (int f = 0; f < 2; ++f) {                        \
        const int o_ = w * 32 + f * 16 + r16;                                \
        AF[f][hh] = *(const short8*)(wb + (size_t)o_ * KTOT +                \
                                     (K) * CIN + hh * 32 + kc); } }
#define MFMA_STEP(K, AF)                                                     \
    { _Pragma("unroll") for (int hh = 0; hh < 2; ++hh) {                     \
        short8 bfr[4];                                                       \
        _Pragma("unroll") for (int nf = 0; nf < 4; ++nf) {                   \
            const int p_ = nf * 16 + r16;                                    \
            const int sl_ = (hh * 4 + q) ^ (p_ & 7);                         \
            bfr[nf] = *(const short8*)(&sB[(K) & 1][p_ * 64 + sl_ * 8]);     \
        }                                                                    \
        _Pragma("unroll") for (int f = 0; f < 2; ++f)                        \
        _Pragma("unroll") for (int nf = 0; nf < 4; ++nf)                     \
            acc[f][nf] = __builtin_amdgcn_mfma_f32_16x16x32_bf16(            \
                AF[f][hh], bfr[nf], acc[f][nf], 0, 0, 0);                    \
    } }

#define BODY(K, WSET, ANEXT, ACUR)                                           \
    {                                                                        \
        __syncthreads();                                                     \
        if ((K) + 1 < NK) WRITEB(WSET, &sB[((K) + 1) & 1][0])                \
        if ((K) + 1 < NK) A_LOAD((K) + 1, ANEXT)                             \
        if ((K) + 3 < NK) GATHER((K) + 3, WSET)                              \
        __syncthreads();                                                     \
        MFMA_STEP(K, ACUR)                                                   \
    }

    // prologue: buf0 staged; g(1)->rgB, g(2)->rgA in flight; A(0) loaded
    GATHER(0, rgA)
    WRITEB(rgA, &sB[0][0])
    A_LOAD(0, afA)
    GATHER(1, rgB)
    GATHER(2, rgA)

    for (int k = 0; k < NK - 1; k += 2) {   // k = 0,2,...,24
        BODY(k,     rgB, afB, afA)
        BODY(k + 1, rgA, afA, afB)
    }
    BODY(26, rgB, afB, afA)                  // guards disable WR/A/G

#undef GATHER
#undef WRITEB
#undef A_LOAD
#undef MFMA_STEP
#undef BODY

    // epilogue: C/D layout: col(n) = lane&15, row(o) = q*4 + r
#pragma unroll
    for (int f = 0; f < 2; ++f)
#pragma unroll
        for (int nf = 0; nf < 4; ++nf)
#pragma unroll
            for (int r = 0; r < 4; ++r) {
                const int o = w * 32 + f * 16 + q * 4 + r;
                const int n = n0 + nf * 16 + r16;
                out[(size_t)o * H + n] = acc[f][nf][r];
            }

    // BN partials: wave-level shfl reduce (16-lane groups), stash in LDS,
    // one coalesced 1KB store per block. NO atomics.
    float* red = (float*)sIdx;        // reuse; all gathers done
    __syncthreads();
#pragma unroll
    for (int f = 0; f < 2; ++f)
#pragma unroll
        for (int r = 0; r < 4; ++r) {
            float sv = acc[f][0][r] + acc[f][1][r] + acc[f][2][r] + acc[f][3][r];
            float sq = acc[f][0][r] * acc[f][0][r] + acc[f][1][r] * acc[f][1][r]
                     + acc[f][2][r] * acc[f][2][r] + acc[f][3][r] * acc[f][3][r];
#pragma unroll
            for (int m = 1; m < 16; m <<= 1) {
                sv += __shfl_xor(sv, m, 64);
                sq += __shfl_xor(sq, m, 64);
            }
            if (r16 == 0) {
                const int o = w * 32 + f * 16 + q * 4 + r;
                red[o] = sv;
                red[COUT + o] = sq;
            }
        }
    __syncthreads();
    part[(size_t)blockIdx.x * 256 + tid] = red[tid];
}

// ---------------------------------------------------------------------------
// Kernel 2b: fold 1024 per-block partials into sums[256]. Coalesced reads;
// 16 atomics per address total (negligible).
__global__ __launch_bounds__(256) void bn_reduce(const float* __restrict__ part,
                                                 float* __restrict__ sums) {
    const int tid = threadIdx.x;
    float s = 0.f;
    const int b0 = blockIdx.x * (NBLOCKS / 16);
    for (int b = b0; b < b0 + NBLOCKS / 16; ++b)
        s += part[(size_t)b * 256 + tid];
    atomicAdd(&sums[tid], s);
}

// ---------------------------------------------------------------------------
// Kernel 3: BN + ReLU with inline stats, float4.
__global__ __launch_bounds__(256) void bn_relu(float* __restrict__ out,
                                               const float* __restrict__ sums,
                                               const float* __restrict__ gamma,
                                               const float* __restrict__ beta) {
    const int idx = blockIdx.x * 256 + threadIdx.x;  // float4 index
    const int o = idx >> 14;                          // 16384 float4 per channel
    const float mean = sums[o] * (1.f / (float)H);
    const float var  = sums[COUT + o] * (1.f / (float)H) - mean * mean;
    const float a = gamma[o] * rsqrtf(var + 1e-5f);
    const float b = beta[o] - mean * a;
    float4* p = (float4*)out;
    float4 v = p[idx];
    v.x = fmaxf(fmaf(v.x, a, b), 0.f);
    v.y = fmaxf(fmaf(v.y, a, b), 0.f);
    v.z = fmaxf(fmaf(v.z, a, b), 0.f);
    v.w = fmaxf(fmaf(v.w, a, b), 0.f);
    p[idx] = v;
}

// ---------------------------------------------------------------------------
extern "C" void kernel_launch(void* const* d_in, const int* in_sizes, int n_in,
                              void* d_out, int out_size, void* d_ws, size_t ws_size,
                              hipStream_t stream) {
    const float* x     = (const float*)d_in[0];  // (1,64,65536,1)
    const int*   neigh = (const int*)d_in[1];    // (65536,27)
    const float* w     = (const float*)d_in[2];  // (128,64,27)
    const float* gamma = (const float*)d_in[3];
    const float* beta  = (const float*)d_in[4];
    float* out = (float*)d_out;                  // (1,128,65536,1)

    char* ws = (char*)d_ws;
    u16* xt  = (u16*)ws;                              // 8388608 B
    u16* wb  = (u16*)(ws + 8388608);                  // 442368 B
    float* sums = (float*)(ws + 8830976);             // 1024 B
    float* part = (float*)(ws + 8832000);             // 1 MB

    transpose_x<<<H / 256, 256, 0, stream>>>(x, xt);
    conv_w<<<(COUT * KTOT + 255) / 256, 256, 0, stream>>>(w, wb, sums);
    conv_mfma<<<NBLOCKS, 256, 0, stream>>>(xt, wb, neigh, out, part);
    bn_reduce<<<16, 256, 0, stream>>>(part, sums);
    bn_relu<<<(COUT * H / 4) / 256, 256, 0, stream>>>(out, sums, gamma, beta);
}

// Round 9
// 89.518 us; speedup vs baseline: 1.7329x; 1.0168x over previous
//
#include <hip/hip_runtime.h>

#define H 65536
#define CIN 64
#define COUT 128
#define NK 27
#define KTOT (NK*CIN)   // 1728
#define NBLK 64         // points per block; 8 waves, each 16o x 64n
#define NBLOCKS (H/NBLK) // 1024

typedef unsigned short u16;
typedef unsigned int   u32;
typedef __attribute__((ext_vector_type(8))) short short8;   // 8 bf16 (MFMA frag)
typedef __attribute__((ext_vector_type(4))) float f32x4;    // MFMA acc
typedef __attribute__((ext_vector_type(4))) unsigned int u32x4;

__device__ __forceinline__ u16 f2bf(float f) {
    u32 u = __float_as_uint(f);
    u = (u + 0x7FFFu + ((u >> 16) & 1u)) >> 16;   // RNE
    return (u16)u;
}

// ---------------------------------------------------------------------------
// Kernel 1a: x (64 x 65536 f32, c-major) -> x_t (65536 x 64 bf16, point-major)
__global__ __launch_bounds__(256) void transpose_x(const float* __restrict__ x,
                                                   u16* __restrict__ xt) {
    const int h = blockIdx.x * 256 + threadIdx.x;
    u32 pk[32];
#pragma unroll
    for (int cp = 0; cp < 32; ++cp) {
        float f0 = x[(2 * cp)     * H + h];
        float f1 = x[(2 * cp + 1) * H + h];
        pk[cp] = (u32)f2bf(f0) | ((u32)f2bf(f1) << 16);
    }
    u32x4* dst = (u32x4*)(xt + (size_t)h * CIN);
#pragma unroll
    for (int i = 0; i < 8; ++i)
        dst[i] = *(u32x4*)&pk[i * 4];
}

// ---------------------------------------------------------------------------
// Kernel 1b: w (128 x 64 x 27 f32) -> wb[o][k*64+c] bf16. Also zeroes BN sums.
__global__ __launch_bounds__(256) void conv_w(const float* __restrict__ w,
                                              u16* __restrict__ wb,
                                              float* __restrict__ sums) {
    const int tid = blockIdx.x * 256 + threadIdx.x;
    if (blockIdx.x == 0) sums[threadIdx.x] = 0.f;   // sum[128], sumsq[128]
    if (tid < COUT * KTOT) {
        const int o = tid / KTOT;
        const int rem = tid - o * KTOT;
        const int k = rem >> 6;
        const int c = rem & 63;
        wb[tid] = f2bf(w[o * KTOT + c * NK + k]);
    }
}

// ---------------------------------------------------------------------------
// Kernel 2: R8's data path, 8-wave blocks for 32 waves/CU (occupancy lever).
// Wave = 16o x 64n. Per body: 1 gather, 1 ds_write, 2 A loads, 8 ds_reads,
// 8 MFMA. 3-deep gather pipeline (queue-order-correct). Zero atomics.
__global__ __launch_bounds__(512, 8) void conv_mfma(const u16* __restrict__ xt,
                                                    const u16* __restrict__ wb,
                                                    const int* __restrict__ neigh,
                                                    float* __restrict__ out,
                                                    float* __restrict__ part) {
    __shared__ __align__(16) u16 sB[2][NBLK * CIN];  // 2 x 8 KB, XOR-swizzled
    __shared__ int sIdx[NBLK * NK];                  // 6912 B (reused as f32[256])

    const int tid  = threadIdx.x;
    const int lane = tid & 63;
    const int w    = tid >> 6;        // wave 0..7 -> o-range w*16..+15
    const int n0   = blockIdx.x * NBLK;

    for (int i = tid; i < NBLK * NK; i += 512)
        sIdx[i] = neigh[n0 * NK + i];
    __syncthreads();

    const int r16 = lane & 15;
    const int q   = lane >> 4;        // 0..3
    const int kc  = q * 8;
    const int pl  = lane >> 3;        // 0..7 row-within-8
    const int cl  = lane & 7;         // 16B chunk within 128B row

    f32x4 acc[4] = {};                // [n-frag]

    u32x4 rgA, rgB;                   // 2 sets carry a 3-deep pipeline
    short8 afA[2], afB[2];            // A double buffer [hh]

#define GATHER(K, RG)                                                        \
    {   const int p_ = w * 8 + pl;                                           \
        const int row_ = sIdx[p_ * NK + (K)];                                \
        RG = *(const u32x4*)(xt + (size_t)(u32)row_ * 64 + cl * 8); }
#define WRITEB(RG, BUF)                                                      \
    {   const int p_ = w * 8 + pl;                                           \
        *(u32x4*)((BUF) + p_ * 64 + ((cl ^ pl) * 8)) = RG; }
#define A_LOAD(K, AF)                                                        \
    { _Pragma("unroll") for (int hh = 0; hh < 2; ++hh) {                     \
        const int o_ = w * 16 + r16;                                         \
        AF[hh] = *(const short8*)(wb + (size_t)o_ * KTOT +                   \
                                  (K) * CIN + hh * 32 + kc); } }
#define MFMA_STEP(K, AF)                                                     \
    { _Pragma("unroll") for (int hh = 0; hh < 2; ++hh) {                     \
        short8 bfr[4];                                                       \
        _Pragma("unroll") for (int nf = 0; nf < 4; ++nf) {                   \
            const int p_ = nf * 16 + r16;                                    \
            const int sl_ = (hh * 4 + q) ^ (p_ & 7);                         \
            bfr[nf] = *(const short8*)(&sB[(K) & 1][p_ * 64 + sl_ * 8]);     \
        }                                                                    \
        _Pragma("unroll") for (int nf = 0; nf < 4; ++nf)                     \
            acc[nf] = __builtin_amdgcn_mfma_f32_16x16x32_bf16(               \
                AF[hh], bfr[nf], acc[nf], 0, 0, 0);                          \
    } }

#define BODY(K, WSET, ANEXT, ACUR)                                           \
    {                                                                        \
        __syncthreads();                                                     \
        if ((K) + 1 < NK) WRITEB(WSET, &sB[((K) + 1) & 1][0])                \
        if ((K) + 1 < NK) A_LOAD((K) + 1, ANEXT)                             \
        if ((K) + 3 < NK) GATHER((K) + 3, WSET)                              \
        __syncthreads();                                                     \
        MFMA_STEP(K, ACUR)                                                   \
    }

    // prologue: buf0 staged; g(1)->rgB, g(2)->rgA in flight; A(0) loaded
    GATHER(0, rgA)
    WRITEB(rgA, &sB[0][0])
    A_LOAD(0, afA)
    GATHER(1, rgB)
    GATHER(2, rgA)

    for (int k = 0; k < NK - 1; k += 2) {   // k = 0,2,...,24
        BODY(k,     rgB, afB, afA)
        BODY(k + 1, rgA, afA, afB)
    }
    BODY(26, rgB, afB, afA)                  // guards disable WR/A/G

#undef GATHER
#undef WRITEB
#undef A_LOAD
#undef MFMA_STEP
#undef BODY

    // epilogue: C/D layout: col(n) = lane&15, row(o) = q*4 + r
#pragma unroll
    for (int nf = 0; nf < 4; ++nf)
#pragma unroll
        for (int r = 0; r < 4; ++r) {
            const int o = w * 16 + q * 4 + r;
            const int n = n0 + nf * 16 + r16;
            out[(size_t)o * H + n] = acc[nf][r];
        }

    // BN partials: 16-lane shfl reduce, stash in LDS, one coalesced store.
    float* red = (float*)sIdx;        // reuse; all gathers done
    __syncthreads();
#pragma unroll
    for (int r = 0; r < 4; ++r) {
        float sv = acc[0][r] + acc[1][r] + acc[2][r] + acc[3][r];
        float sq = acc[0][r] * acc[0][r] + acc[1][r] * acc[1][r]
                 + acc[2][r] * acc[2][r] + acc[3][r] * acc[3][r];
#pragma unroll
        for (int m = 1; m < 16; m <<= 1) {
            sv += __shfl_xor(sv, m, 64);
            sq += __shfl_xor(sq, m, 64);
        }
        if (r16 == 0) {
            const int o = w * 16 + q * 4 + r;
            red[o] = sv;
            red[COUT + o] = sq;
        }
    }
    __syncthreads();
    if (tid < 256)
        part[(size_t)blockIdx.x * 256 + tid] = red[tid];
}

// ---------------------------------------------------------------------------
// Kernel 2b: fold 1024 per-block partials into sums[256]. 16 atomics/address.
__global__ __launch_bounds__(256) void bn_reduce(const float* __restrict__ part,
                                                 float* __restrict__ sums) {
    const int tid = threadIdx.x;
    float s = 0.f;
    const int b0 = blockIdx.x * (NBLOCKS / 16);
    for (int b = b0; b < b0 + NBLOCKS / 16; ++b)
        s += part[(size_t)b * 256 + tid];
    atomicAdd(&sums[tid], s);
}

// ---------------------------------------------------------------------------
// Kernel 3: BN + ReLU with inline stats, float4.
__global__ __launch_bounds__(256) void bn_relu(float* __restrict__ out,
                                               const float* __restrict__ sums,
                                               const float* __restrict__ gamma,
                                               const float* __restrict__ beta) {
    const int idx = blockIdx.x * 256 + threadIdx.x;  // float4 index
    const int o = idx >> 14;                          // 16384 float4 per channel
    const float mean = sums[o] * (1.f / (float)H);
    const float var  = sums[COUT + o] * (1.f / (float)H) - mean * mean;
    const float a = gamma[o] * rsqrtf(var + 1e-5f);
    const float b = beta[o] - mean * a;
    float4* p = (float4*)out;
    float4 v = p[idx];
    v.x = fmaxf(fmaf(v.x, a, b), 0.f);
    v.y = fmaxf(fmaf(v.y, a, b), 0.f);
    v.z = fmaxf(fmaf(v.z, a, b), 0.f);
    v.w = fmaxf(fmaf(v.w, a, b), 0.f);
    p[idx] = v;
}

// ---------------------------------------------------------------------------
extern "C" void kernel_launch(void* const* d_in, const int* in_sizes, int n_in,
                              void* d_out, int out_size, void* d_ws, size_t ws_size,
                              hipStream_t stream) {
    const float* x     = (const float*)d_in[0];  // (1,64,65536,1)
    const int*   neigh = (const int*)d_in[1];    // (65536,27)
    const float* w     = (const float*)d_in[2];  // (128,64,27)
    const float* gamma = (const float*)d_in[3];
    const float* beta  = (const float*)d_in[4];
    float* out = (float*)d_out;                  // (1,128,65536,1)

    char* ws = (char*)d_ws;
    u16* xt  = (u16*)ws;                              // 8388608 B
    u16* wb  = (u16*)(ws + 8388608);                  // 442368 B
    float* sums = (float*)(ws + 8830976);             // 1024 B
    float* part = (float*)(ws + 8832000);             // 1 MB

    transpose_x<<<H / 256, 256, 0, stream>>>(x, xt);
    conv_w<<<(COUT * KTOT + 255) / 256, 256, 0, stream>>>(w, wb, sums);
    conv_mfma<<<NBLOCKS, 512, 0, stream>>>(xt, wb, neigh, out, part);
    bn_reduce<<<16, 256, 0, stream>>>(part, sums);
    bn_relu<<<(COUT * H / 4) / 256, 256, 0, stream>>>(out, sums, gamma, beta);
}